// Round 4
// baseline (291.566 us; speedup 1.0000x reference)
//
#include <hip/hip_runtime.h>
#include <hip/hip_bf16.h>
#include <math.h>

// Problem constants (from reference setup_inputs):
//   support [25, 2560] fp32, query [4096, 2560] fp32, n_way=5, k_shot=5
//   out [4096, 5] fp32 = -dist.reshape(4096,5,5).sum(-1)
//   dist[q][s] = || support[s] - query[q] + 1e-6 ||_2
// Strategy: dist^2 = ||s+eps||^2 - 2*(s.q + eps*sum(q)) + ||q||^2
//   -> 1 FMA per (q,s,d) element.
//
// R3 post-mortem: spill fixed (acc[60]/thread fits the allocator's 128-VGPR
// choice), kernel ~22 us but grid-limited to 2 waves/SIMD (1024 blocks x 2
// waves = 8 waves/CU) -> L2 latency (~200cyc) not hidden. R4: same per-thread
// shape, but 4 waves/block as (sup-group sg x d-half dg): sg in {0,1} takes 13
// supports (1-row overlap), dg in {0,1} takes alternating 256-float d-chunks.
// Occupancy 2 -> 4 waves/SIMD, identical L2 traffic.

#define EPS 1e-6f
#define D 2560
#define NSUP 25
#define NQ 4096
#define NWAY 5
#define KSHOT 5

#define QR 4           // query rows per block
#define BT 256         // 4 waves: (sg, dg)
#define KITER 5        // d-chunks per wave (10 total, alternating by dg)
#define NSL 13         // supports per sup-group (sg0: 0-12, sg1: 12-24)
#define NACC 60        // 52 dots + 4 sumq + 4 normq
#define PH 30          // reduction values per phase
#define STRIDE 31      // odd -> <=2-way LDS bank aliasing (free)

// ---- prep: ns[s] = || support[s] + eps ||^2  (25 floats into workspace) ----
__global__ void prep_kernel(const float* __restrict__ sup, float* __restrict__ ns) {
    const int s = blockIdx.x;
    const int t = threadIdx.x;  // 256 threads
    float p = 0.f;
    #pragma unroll
    for (int k = 0; k < 10; ++k) {
        float v = sup[s * D + t + 256 * k] + EPS;
        p += v * v;
    }
    __shared__ float red[256];
    red[t] = p;
    __syncthreads();
    for (int off = 128; off > 0; off >>= 1) {
        if (t < off) red[t] += red[t + off];
        __syncthreads();
    }
    if (t == 0) ns[s] = red[0];
}

// ---- main: QR query rows per block; waves = (sup-group) x (d-half) ----
__global__ __launch_bounds__(BT, 4)
void pairwise_kernel(const float* __restrict__ q, const float* __restrict__ sup,
                     const float* __restrict__ ns, float* __restrict__ out) {
    const int t = threadIdx.x;
    const int lane = t & 63;
    const int wave = t >> 6;          // 0..3
    const int sg = wave >> 1;         // support group: 0 -> sups 0-12, 1 -> 12-24
    const int dg = wave & 1;          // d-interleave: chunks k = 2j+dg
    const int row0 = blockIdx.x * QR;
    const int sup_base = sg * (NSL - 1);   // 0 or 12

    // acc[r*13+j] = partial dot(support[sup_base+j], query[row0+r])
    // acc[52+r]   = partial sum(query[row0+r])     (summed over both dg waves)
    // acc[56+r]   = partial ||query[row0+r]||^2
    float acc[NACC];
    #pragma unroll
    for (int i = 0; i < NACC; ++i) acc[i] = 0.f;

    #pragma unroll 1                      // do NOT unroll: bounds register pressure
    for (int j = 0; j < KITER; ++j) {
        const int idx = 4 * lane + 512 * j + 256 * dg;  // float index, 16B-aligned
        float4 q4[QR];
        #pragma unroll
        for (int r = 0; r < QR; ++r)
            q4[r] = *reinterpret_cast<const float4*>(&q[(row0 + r) * D + idx]);
        #pragma unroll
        for (int r = 0; r < QR; ++r) {
            acc[52 + r] += (q4[r].x + q4[r].y) + (q4[r].z + q4[r].w);
            acc[56 + r] += q4[r].x * q4[r].x + q4[r].y * q4[r].y
                         + q4[r].z * q4[r].z + q4[r].w * q4[r].w;
        }
        // 13 supports in groups of 4 (4,4,4,1): caps in-flight loads at 16 VGPRs
        #pragma unroll
        for (int g = 0; g < NSL; g += 4) {
            const int ge = (g + 4 < NSL) ? g + 4 : NSL;
            float4 a4[4];
            #pragma unroll
            for (int jj = g; jj < ge; ++jj)
                a4[jj - g] = *reinterpret_cast<const float4*>(&sup[(sup_base + jj) * D + idx]);
            #pragma unroll
            for (int jj = g; jj < ge; ++jj) {
                #pragma unroll
                for (int r = 0; r < QR; ++r) {
                    acc[r * NSL + jj] += a4[jj - g].x * q4[r].x + a4[jj - g].y * q4[r].y
                                       + a4[jj - g].z * q4[r].z + a4[jj - g].w * q4[r].w;
                }
            }
        }
    }

    // ---- cross-thread reduction: LDS transpose, 2 phases of 30 columns ----
    // Columns for sup-group sg are summed over that sg's 128 threads (both dg
    // halves combine for free).
    __shared__ float buf[BT * STRIDE];   // 31744 B
    __shared__ float red0[NACC];         // sg0 sums (sups 0-12 + full-D q stats)
    __shared__ float red1[NACC];         // sg1 sums (sups 12-24)
    __shared__ float dist[100];

    #pragma unroll 1
    for (int p = 0; p < 2; ++p) {
        #pragma unroll
        for (int v = 0; v < PH; ++v) buf[t * STRIDE + v] = acc[p * PH + v];
        __syncthreads();
        // wave0 lanes reduce sg0 (rows 0-127), wave2 lanes reduce sg1 (rows 128-255)
        if ((wave == 0 || wave == 2) && lane < PH) {
            const int base = (wave >> 1) * 128;
            float s0 = 0.f, s1 = 0.f, s2 = 0.f, s3 = 0.f;
            for (int i = 0; i < 128; i += 4) {
                s0 += buf[(base + i + 0) * STRIDE + lane];
                s1 += buf[(base + i + 1) * STRIDE + lane];
                s2 += buf[(base + i + 2) * STRIDE + lane];
                s3 += buf[(base + i + 3) * STRIDE + lane];
            }
            const float tot = (s0 + s1) + (s2 + s3);
            if (wave == 0) red0[p * PH + lane] = tot;
            else           red1[p * PH + lane] = tot;
        }
        __syncthreads();
    }

    // ---- epilogue: dist = sqrt(ns + ||q||^2 - 2*(dot + eps*sumq)) ----
    if (t < 100) {
        const int r = t / NSUP, s = t % NSUP;
        const float dot = (s < NSL) ? red0[r * NSL + s] : red1[r * NSL + (s - (NSL - 1))];
        const float d2 = ns[s] + red0[56 + r] - 2.f * (dot + EPS * red0[52 + r]);
        dist[t] = sqrtf(fmaxf(d2, 0.f));
    }
    __syncthreads();
    if (t < QR * NWAY) {
        const int r = t / NWAY, w = t % NWAY;
        float sc = 0.f;
        #pragma unroll
        for (int j = 0; j < KSHOT; ++j) sc += dist[r * NSUP + w * KSHOT + j];
        out[(row0 + r) * NWAY + w] = -sc;
    }
}

extern "C" void kernel_launch(void* const* d_in, const int* in_sizes, int n_in,
                              void* d_out, int out_size, void* d_ws, size_t ws_size,
                              hipStream_t stream) {
    const float* support = (const float*)d_in[0];
    const float* query   = (const float*)d_in[1];
    // d_in[2]=n_way(5), d_in[3]=k_shot(5): hardcoded per setup_inputs.
    float* out = (float*)d_out;
    float* ns  = (float*)d_ws;   // 25 floats of scratch

    prep_kernel<<<NSUP, 256, 0, stream>>>(support, ns);
    pairwise_kernel<<<NQ / QR, BT, 0, stream>>>(query, support, ns, out);
}

// Round 5
// 136.731 us; speedup vs baseline: 2.1324x; 2.1324x over previous
//
#include <hip/hip_runtime.h>
#include <hip/hip_bf16.h>
#include <math.h>

// Problem constants (from reference setup_inputs):
//   support [25, 2560] fp32, query [4096, 2560] fp32, n_way=5, k_shot=5
//   out [4096, 5] fp32 = -dist.reshape(4096,5,5).sum(-1)
//   dist[q][s] = || support[s] - query[q] + 1e-6 ||_2
// Strategy: dist^2 = ||s+eps||^2 - 2*(s.q + eps*sum(q)) + ||q||^2
//   -> 1 FMA per (q,s,d) element.
//
// R4 post-mortem: __launch_bounds__(256,4) made the allocator pick 64 VGPRs
// -> acc[60] spilled (489 MB scratch writes, 220 us). The minWavesPerEU arg
// is over-honored: (B) or (B,2) -> 128 VGPRs (R2/R3, no spill at acc[60]);
// (B,4) -> 64 (fatal). R5 = R4 with launch_bounds(256,2). Design: 4 waves =
// (sup-group sg x d-half dg); sg in {0,1} takes 13 supports (1-row overlap),
// dg in {0,1} takes alternating 256-float d-chunks. 1024 blocks x 4 waves =
// 4 waves/SIMD (vs R3's 2), identical L2 traffic (~354 MB -> 9.6 us floor).

#define EPS 1e-6f
#define D 2560
#define NSUP 25
#define NQ 4096
#define NWAY 5
#define KSHOT 5

#define QR 4           // query rows per block
#define BT 256         // 4 waves: (sg, dg)
#define KITER 5        // d-chunks per wave (10 total, alternating by dg)
#define NSL 13         // supports per sup-group (sg0: 0-12, sg1: 12-24)
#define NACC 60        // 52 dots + 4 sumq + 4 normq
#define PH 30          // reduction values per phase
#define STRIDE 31      // odd -> <=2-way LDS bank aliasing (free)

// ---- prep: ns[s] = || support[s] + eps ||^2  (25 floats into workspace) ----
__global__ void prep_kernel(const float* __restrict__ sup, float* __restrict__ ns) {
    const int s = blockIdx.x;
    const int t = threadIdx.x;  // 256 threads
    float p = 0.f;
    #pragma unroll
    for (int k = 0; k < 10; ++k) {
        float v = sup[s * D + t + 256 * k] + EPS;
        p += v * v;
    }
    __shared__ float red[256];
    red[t] = p;
    __syncthreads();
    for (int off = 128; off > 0; off >>= 1) {
        if (t < off) red[t] += red[t + off];
        __syncthreads();
    }
    if (t == 0) ns[s] = red[0];
}

// ---- main: QR query rows per block; waves = (sup-group) x (d-half) ----
__global__ __launch_bounds__(BT, 2)   // NOT (BT,4): that forces a 64-VGPR budget and spills
void pairwise_kernel(const float* __restrict__ q, const float* __restrict__ sup,
                     const float* __restrict__ ns, float* __restrict__ out) {
    const int t = threadIdx.x;
    const int lane = t & 63;
    const int wave = t >> 6;          // 0..3
    const int sg = wave >> 1;         // support group: 0 -> sups 0-12, 1 -> 12-24
    const int dg = wave & 1;          // d-interleave: chunks k = 2j+dg
    const int row0 = blockIdx.x * QR;
    const int sup_base = sg * (NSL - 1);   // 0 or 12

    // acc[r*13+j] = partial dot(support[sup_base+j], query[row0+r])
    // acc[52+r]   = partial sum(query[row0+r])     (summed over both dg waves)
    // acc[56+r]   = partial ||query[row0+r]||^2
    float acc[NACC];
    #pragma unroll
    for (int i = 0; i < NACC; ++i) acc[i] = 0.f;

    #pragma unroll 1                      // do NOT unroll: bounds register pressure
    for (int j = 0; j < KITER; ++j) {
        const int idx = 4 * lane + 512 * j + 256 * dg;  // float index, 16B-aligned
        float4 q4[QR];
        #pragma unroll
        for (int r = 0; r < QR; ++r)
            q4[r] = *reinterpret_cast<const float4*>(&q[(row0 + r) * D + idx]);
        #pragma unroll
        for (int r = 0; r < QR; ++r) {
            acc[52 + r] += (q4[r].x + q4[r].y) + (q4[r].z + q4[r].w);
            acc[56 + r] += q4[r].x * q4[r].x + q4[r].y * q4[r].y
                         + q4[r].z * q4[r].z + q4[r].w * q4[r].w;
        }
        // 13 supports in groups of 4 (4,4,4,1): caps in-flight loads at 16 VGPRs
        #pragma unroll
        for (int g = 0; g < NSL; g += 4) {
            const int ge = (g + 4 < NSL) ? g + 4 : NSL;
            float4 a4[4];
            #pragma unroll
            for (int jj = g; jj < ge; ++jj)
                a4[jj - g] = *reinterpret_cast<const float4*>(&sup[(sup_base + jj) * D + idx]);
            #pragma unroll
            for (int jj = g; jj < ge; ++jj) {
                #pragma unroll
                for (int r = 0; r < QR; ++r) {
                    acc[r * NSL + jj] += a4[jj - g].x * q4[r].x + a4[jj - g].y * q4[r].y
                                       + a4[jj - g].z * q4[r].z + a4[jj - g].w * q4[r].w;
                }
            }
        }
    }

    // ---- cross-thread reduction: LDS transpose, 2 phases of 30 columns ----
    // Columns for sup-group sg are summed over that sg's 128 threads (both dg
    // halves combine for free).
    __shared__ float buf[BT * STRIDE];   // 31744 B
    __shared__ float red0[NACC];         // sg0 sums (sups 0-12 + full-D q stats)
    __shared__ float red1[NACC];         // sg1 sums (sups 12-24)
    __shared__ float dist[100];

    #pragma unroll 1
    for (int p = 0; p < 2; ++p) {
        #pragma unroll
        for (int v = 0; v < PH; ++v) buf[t * STRIDE + v] = acc[p * PH + v];
        __syncthreads();
        // wave0 lanes reduce sg0 (rows 0-127), wave2 lanes reduce sg1 (rows 128-255)
        if ((wave == 0 || wave == 2) && lane < PH) {
            const int base = (wave >> 1) * 128;
            float s0 = 0.f, s1 = 0.f, s2 = 0.f, s3 = 0.f;
            for (int i = 0; i < 128; i += 4) {
                s0 += buf[(base + i + 0) * STRIDE + lane];
                s1 += buf[(base + i + 1) * STRIDE + lane];
                s2 += buf[(base + i + 2) * STRIDE + lane];
                s3 += buf[(base + i + 3) * STRIDE + lane];
            }
            const float tot = (s0 + s1) + (s2 + s3);
            if (wave == 0) red0[p * PH + lane] = tot;
            else           red1[p * PH + lane] = tot;
        }
        __syncthreads();
    }

    // ---- epilogue: dist = sqrt(ns + ||q||^2 - 2*(dot + eps*sumq)) ----
    if (t < 100) {
        const int r = t / NSUP, s = t % NSUP;
        const float dot = (s < NSL) ? red0[r * NSL + s] : red1[r * NSL + (s - (NSL - 1))];
        const float d2 = ns[s] + red0[56 + r] - 2.f * (dot + EPS * red0[52 + r]);
        dist[t] = sqrtf(fmaxf(d2, 0.f));
    }
    __syncthreads();
    if (t < QR * NWAY) {
        const int r = t / NWAY, w = t % NWAY;
        float sc = 0.f;
        #pragma unroll
        for (int j = 0; j < KSHOT; ++j) sc += dist[r * NSUP + w * KSHOT + j];
        out[(row0 + r) * NWAY + w] = -sc;
    }
}

extern "C" void kernel_launch(void* const* d_in, const int* in_sizes, int n_in,
                              void* d_out, int out_size, void* d_ws, size_t ws_size,
                              hipStream_t stream) {
    const float* support = (const float*)d_in[0];
    const float* query   = (const float*)d_in[1];
    // d_in[2]=n_way(5), d_in[3]=k_shot(5): hardcoded per setup_inputs.
    float* out = (float*)d_out;
    float* ns  = (float*)d_ws;   // 25 floats of scratch

    prep_kernel<<<NSUP, 256, 0, stream>>>(support, ns);
    pairwise_kernel<<<NQ / QR, BT, 0, stream>>>(query, support, ns, out);
}

// Round 6
// 101.725 us; speedup vs baseline: 2.8662x; 1.3441x over previous
//
#include <hip/hip_runtime.h>
#include <hip/hip_bf16.h>
#include <math.h>

// Problem constants (from reference setup_inputs):
//   support [25, 2560] fp32, query [4096, 2560] fp32, n_way=5, k_shot=5
//   out [4096, 5] fp32 = -dist.reshape(4096,5,5).sum(-1)
//   dist[q][s] = || support[s] - query[q] + 1e-6 ||_2
// Strategy: dist^2 = ||s+eps||^2 - 2*(s.q + eps*sum(q)) + ||q||^2
//   -> 1 FMA per (q,s,d) element.
//
// R5 post-mortem: WRITE_SIZE still 113 MB at VGPR=120. Root cause found: the
// reduction's phase loop was `#pragma unroll 1`, so acc[p*PH+v] is a DYNAMIC
// index into the register array -> SROA fails -> the whole acc array lives in
// scratch (present since R2!). R6: fully unroll the 2-iteration phase loop so
// every acc index is compile-time. Everything else unchanged from R5.
// Design: 4 waves = (sup-group sg x d-half dg); sg in {0,1} takes 13 supports
// (1-row overlap), dg in {0,1} takes alternating 256-float d-chunks.
// 1024 blocks x 4 waves = 4 waves/SIMD; L2 traffic ~344 MB -> 9.3 us floor.

#define EPS 1e-6f
#define D 2560
#define NSUP 25
#define NQ 4096
#define NWAY 5
#define KSHOT 5

#define QR 4           // query rows per block
#define BT 256         // 4 waves: (sg, dg)
#define KITER 5        // d-chunks per wave (10 total, alternating by dg)
#define NSL 13         // supports per sup-group (sg0: 0-12, sg1: 12-24)
#define NACC 60        // 52 dots + 4 sumq + 4 normq
#define PH 30          // reduction values per phase
#define STRIDE 31      // odd -> <=2-way LDS bank aliasing (free)

// ---- prep: ns[s] = || support[s] + eps ||^2  (25 floats into workspace) ----
__global__ void prep_kernel(const float* __restrict__ sup, float* __restrict__ ns) {
    const int s = blockIdx.x;
    const int t = threadIdx.x;  // 256 threads
    float p = 0.f;
    #pragma unroll
    for (int k = 0; k < 10; ++k) {
        float v = sup[s * D + t + 256 * k] + EPS;
        p += v * v;
    }
    __shared__ float red[256];
    red[t] = p;
    __syncthreads();
    for (int off = 128; off > 0; off >>= 1) {
        if (t < off) red[t] += red[t + off];
        __syncthreads();
    }
    if (t == 0) ns[s] = red[0];
}

// ---- main: QR query rows per block; waves = (sup-group) x (d-half) ----
__global__ __launch_bounds__(BT, 2)   // NOT (BT,4): that forces a 64-VGPR budget and spills
void pairwise_kernel(const float* __restrict__ q, const float* __restrict__ sup,
                     const float* __restrict__ ns, float* __restrict__ out) {
    const int t = threadIdx.x;
    const int lane = t & 63;
    const int wave = t >> 6;          // 0..3
    const int sg = wave >> 1;         // support group: 0 -> sups 0-12, 1 -> 12-24
    const int dg = wave & 1;          // d-interleave: chunks k = 2j+dg
    const int row0 = blockIdx.x * QR;
    const int sup_base = sg * (NSL - 1);   // 0 or 12

    // acc[r*13+j] = partial dot(support[sup_base+j], query[row0+r])
    // acc[52+r]   = partial sum(query[row0+r])     (summed over both dg waves)
    // acc[56+r]   = partial ||query[row0+r]||^2
    // ALL acc indices must be compile-time constants (SROA -> registers).
    float acc[NACC];
    #pragma unroll
    for (int i = 0; i < NACC; ++i) acc[i] = 0.f;

    #pragma unroll 1                      // do NOT unroll: bounds register pressure
    for (int j = 0; j < KITER; ++j) {
        const int idx = 4 * lane + 512 * j + 256 * dg;  // float index, 16B-aligned
        float4 q4[QR];
        #pragma unroll
        for (int r = 0; r < QR; ++r)
            q4[r] = *reinterpret_cast<const float4*>(&q[(row0 + r) * D + idx]);
        #pragma unroll
        for (int r = 0; r < QR; ++r) {
            acc[52 + r] += (q4[r].x + q4[r].y) + (q4[r].z + q4[r].w);
            acc[56 + r] += q4[r].x * q4[r].x + q4[r].y * q4[r].y
                         + q4[r].z * q4[r].z + q4[r].w * q4[r].w;
        }
        // 13 supports in groups of 4 (4,4,4,1): caps in-flight loads at 16 VGPRs
        #pragma unroll
        for (int g = 0; g < NSL; g += 4) {
            const int ge = (g + 4 < NSL) ? g + 4 : NSL;
            float4 a4[4];
            #pragma unroll
            for (int jj = g; jj < ge; ++jj)
                a4[jj - g] = *reinterpret_cast<const float4*>(&sup[(sup_base + jj) * D + idx]);
            #pragma unroll
            for (int jj = g; jj < ge; ++jj) {
                #pragma unroll
                for (int r = 0; r < QR; ++r) {
                    acc[r * NSL + jj] += a4[jj - g].x * q4[r].x + a4[jj - g].y * q4[r].y
                                       + a4[jj - g].z * q4[r].z + a4[jj - g].w * q4[r].w;
                }
            }
        }
    }

    // ---- cross-thread reduction: LDS transpose, 2 phases of 30 columns ----
    // Phase loop MUST be fully unrolled: a runtime p makes acc[p*PH+v] a
    // dynamic register-array index -> SROA fails -> acc spills to scratch
    // (this was R2-R5's 113-489 MB WRITE_SIZE).
    __shared__ float buf[BT * STRIDE];   // 31744 B
    __shared__ float red0[NACC];         // sg0 sums (sups 0-12 + full-D q stats)
    __shared__ float red1[NACC];         // sg1 sums (sups 12-24)
    __shared__ float dist[100];

    #pragma unroll
    for (int p = 0; p < 2; ++p) {
        #pragma unroll
        for (int v = 0; v < PH; ++v) buf[t * STRIDE + v] = acc[p * PH + v];
        __syncthreads();
        // wave0 lanes reduce sg0 (rows 0-127), wave2 lanes reduce sg1 (rows 128-255)
        if ((wave == 0 || wave == 2) && lane < PH) {
            const int base = (wave >> 1) * 128;
            float s0 = 0.f, s1 = 0.f, s2 = 0.f, s3 = 0.f;
            for (int i = 0; i < 128; i += 4) {
                s0 += buf[(base + i + 0) * STRIDE + lane];
                s1 += buf[(base + i + 1) * STRIDE + lane];
                s2 += buf[(base + i + 2) * STRIDE + lane];
                s3 += buf[(base + i + 3) * STRIDE + lane];
            }
            const float tot = (s0 + s1) + (s2 + s3);
            if (wave == 0) red0[p * PH + lane] = tot;
            else           red1[p * PH + lane] = tot;
        }
        __syncthreads();
    }

    // ---- epilogue: dist = sqrt(ns + ||q||^2 - 2*(dot + eps*sumq)) ----
    if (t < 100) {
        const int r = t / NSUP, s = t % NSUP;
        const float dot = (s < NSL) ? red0[r * NSL + s] : red1[r * NSL + (s - (NSL - 1))];
        const float d2 = ns[s] + red0[56 + r] - 2.f * (dot + EPS * red0[52 + r]);
        dist[t] = sqrtf(fmaxf(d2, 0.f));
    }
    __syncthreads();
    if (t < QR * NWAY) {
        const int r = t / NWAY, w = t % NWAY;
        float sc = 0.f;
        #pragma unroll
        for (int j = 0; j < KSHOT; ++j) sc += dist[r * NSUP + w * KSHOT + j];
        out[(row0 + r) * NWAY + w] = -sc;
    }
}

extern "C" void kernel_launch(void* const* d_in, const int* in_sizes, int n_in,
                              void* d_out, int out_size, void* d_ws, size_t ws_size,
                              hipStream_t stream) {
    const float* support = (const float*)d_in[0];
    const float* query   = (const float*)d_in[1];
    // d_in[2]=n_way(5), d_in[3]=k_shot(5): hardcoded per setup_inputs.
    float* out = (float*)d_out;
    float* ns  = (float*)d_ws;   // 25 floats of scratch

    prep_kernel<<<NSUP, 256, 0, stream>>>(support, ns);
    pairwise_kernel<<<NQ / QR, BT, 0, stream>>>(query, support, ns, out);
}